// Round 2
// baseline (213.907 us; speedup 1.0000x reference)
//
#include <hip/hip_runtime.h>

// GraphAugmentation fused kernel, MI355X — R2.
//
// Algebra (unchanged from R1):
//  * softmax over 8 identical affinities == uniform 1/8 -> Q/K/attn dead.
//  * agg = conv1x1(mean_of_8_rolls(x), mw, mb)  (roll commutes with 1x1 conv).
//  * out = agg * sigmoid(g2 @ relu(g1 @ [x; agg]))
//
// R2 changes vs R1 (FETCH was 207 MB = 3x input -> cross-XCD L2 miss):
//  * bijective XCD swizzle: 4096 wgs, chunk 512 -> each XCD owns 256
//    contiguous image rows; x rows land in one L2 and get reused 7x.
//  * thread owns adjacent pixels (2t, 2t+1): float2 center loads, float2
//    stores, float2 for the 5 even-dx neighbor offsets (even col -> 8B
//    aligned; odd-dx offsets stay scalar with individual wrap).
//  * neighbor element-offsets precomputed once as 32-bit; channel loop
//    walks a uniform base pointer -> saddr-form loads, no per-load addr math.
//  * 128-thread blocks (2 waves) for smoother residency.

#define HW 262144   // 512*512
#define WD 512

__global__ __launch_bounds__(128) void ga_fused(
    const float* __restrict__ x,
    const float* __restrict__ mw,  const float* __restrict__ mb,
    const float* __restrict__ g1w, const float* __restrict__ g1b,
    const float* __restrict__ g2w, const float* __restrict__ g2b,
    float* __restrict__ out)
{
  // Fixed offsets (dy,dx) from the reference OFFSETS list.
  // dx parity split: even dx at i={0,2,3,6,7}, odd dx at i={1,4,5}.
  constexpr int DY[8] = {-4, -4, -4, -3, -2, 2, 3, 4};
  constexpr int DX[8] = {-4, -1,  2,  4, -3, 3, -2, 4};

  // ---- XCD-aware bijective swizzle: nwg=4096, 8 XCDs, chunk=512 ----
  const int bid = blockIdx.x;
  const int sw  = ((bid & 7) << 9) + (bid >> 3);   // XCD k owns sw in [k*512,(k+1)*512)
  const int b    = sw >> 10;        // 1024 wgs per batch image
  const int r    = (sw >> 1) & 511; // row
  const int half = sw & 1;          // half-row
  const int t    = threadIdx.x;     // 0..127
  const int w0   = (half << 8) + (t << 1);   // even column; thread owns w0, w0+1

  const float* xb = x + b * 16 * HW;
  const int rowbase = r * WD;

  // ---- precompute 32-bit element offsets for the 8 neighbor gathers ----
  unsigned eoff[5];          // even-dx: float2-safe (even col, no intra-pair wrap)
  unsigned o0[3], o1[3];     // odd-dx: per-pixel scalar with wrap
  {
    const int EI[5] = {0, 2, 3, 6, 7};
#pragma unroll
    for (int k = 0; k < 5; ++k) {
      const int i = EI[k];
      eoff[k] = ((r - DY[i]) & 511) * WD + ((w0 - DX[i]) & 511);
    }
    const int OI[3] = {1, 4, 5};
#pragma unroll
    for (int k = 0; k < 3; ++k) {
      const int i = OI[k];
      const unsigned ro = ((r - DY[i]) & 511) * WD;
      o0[k] = ro + ((w0     - DX[i]) & 511);
      o1[k] = ro + ((w0 + 1 - DX[i]) & 511);
    }
  }

  // ---- load center x and compute xavg over the 8 rolled copies ----
  float xc0[16], xc1[16], xa0[16], xa1[16];
#pragma unroll
  for (int c = 0; c < 16; ++c) {
    const float* xp = xb + c * HW;
    const float2 ctr = *reinterpret_cast<const float2*>(xp + rowbase + w0);
    xc0[c] = ctr.x;
    xc1[c] = ctr.y;
    float s0 = 0.f, s1 = 0.f;
#pragma unroll
    for (int k = 0; k < 5; ++k) {
      const float2 v = *reinterpret_cast<const float2*>(xp + eoff[k]);
      s0 += v.x;
      s1 += v.y;
    }
#pragma unroll
    for (int k = 0; k < 3; ++k) {
      s0 += xp[o0[k]];
      s1 += xp[o1[k]];
    }
    xa0[c] = s0 * 0.125f;
    xa1[c] = s1 * 0.125f;
  }

  // ---- agg = mw @ xavg + mb  (16x16) ----
  float ag0[16], ag1[16];
#pragma unroll
  for (int c = 0; c < 16; ++c) {
    float a0 = mb[c], a1 = mb[c];
#pragma unroll
    for (int k = 0; k < 16; ++k) {
      const float wv = mw[c * 16 + k];   // wave-uniform -> scalar load
      a0 = fmaf(wv, xa0[k], a0);
      a1 = fmaf(wv, xa1[k], a1);
    }
    ag0[c] = a0;
    ag1[c] = a1;
  }

  // ---- hidden = relu(g1w @ [x; agg] + g1b)  (32x32) ----
  float hd0[32], hd1[32];
#pragma unroll
  for (int j = 0; j < 32; ++j) {
    float s0 = g1b[j], s1 = g1b[j];
#pragma unroll
    for (int k = 0; k < 16; ++k) {
      const float wx = g1w[j * 32 + k];
      const float wa = g1w[j * 32 + 16 + k];
      s0 = fmaf(wx, xc0[k], s0);
      s0 = fmaf(wa, ag0[k], s0);
      s1 = fmaf(wx, xc1[k], s1);
      s1 = fmaf(wa, ag1[k], s1);
    }
    hd0[j] = fmaxf(s0, 0.f);
    hd1[j] = fmaxf(s1, 0.f);
  }

  // ---- gate = sigmoid(g2w @ hidden + g2b); out = agg * gate  (16x32) ----
  float* ob = out + b * 16 * HW + rowbase;
#pragma unroll
  for (int c = 0; c < 16; ++c) {
    float s0 = g2b[c], s1 = g2b[c];
#pragma unroll
    for (int j = 0; j < 32; ++j) {
      const float wv = g2w[c * 32 + j];
      s0 = fmaf(wv, hd0[j], s0);
      s1 = fmaf(wv, hd1[j], s1);
    }
    const float gt0 = 1.0f / (1.0f + __expf(-s0));
    const float gt1 = 1.0f / (1.0f + __expf(-s1));
    float2 o;
    o.x = ag0[c] * gt0;
    o.y = ag1[c] * gt1;
    *reinterpret_cast<float2*>(ob + c * HW + w0) = o;
  }
}

extern "C" void kernel_launch(void* const* d_in, const int* in_sizes, int n_in,
                              void* d_out, int out_size, void* d_ws, size_t ws_size,
                              hipStream_t stream) {
  // setup_inputs() order:
  // 0:x 1:qw 2:qb 3:kw 4:kb 5:mw 6:mb 7:scaling 8:g1w 9:g1b 10:g2w 11:g2b
  const float* x   = (const float*)d_in[0];
  const float* mw  = (const float*)d_in[5];
  const float* mb  = (const float*)d_in[6];
  const float* g1w = (const float*)d_in[8];
  const float* g1b = (const float*)d_in[9];
  const float* g2w = (const float*)d_in[10];
  const float* g2b = (const float*)d_in[11];
  float* out = (float*)d_out;

  // 4096 wgs x 128 threads; each wg = half an image row (256 px, 2 px/thread).
  ga_fused<<<4096, 128, 0, stream>>>(x, mw, mb, g1w, g1b, g2w, g2b, out);
}